// Round 1
// baseline (814.974 us; speedup 1.0000x reference)
//
#include <hip/hip_runtime.h>
#include <math.h>

#define PI_F 3.14159265358979323846f

// ---- static config ----
// B=2, HRV=32, WRV=1024, CRV=64; CB=256, HB=200, WB=200
// D=128, COUT=128, HEADS=8, POINTS=6, DH=16
// M = B*HRV*WRV = 65536 rows, nq per batch = 32768
// NV = HB*WB = 40000

__device__ __forceinline__ float gelu_f(float x) {
    return 0.5f * x * (1.0f + erff(x * 0.70710678118654752440f));
}

// ---------------- az sin/cos table ----------------
__global__ void azsc_kernel(float2* __restrict__ azsc) {
    int w = blockIdx.x * 256 + threadIdx.x;
    if (w < 1024) {
        float az = -PI_F + (float)w * (6.283185307179586f / 1024.0f);
        azsc[w] = make_float2(sinf(az), cosf(az));
    }
}

// ---------------- fused weight prep ----------------
// pvvp_w[256][128] = pv_w @ vp_w ; pvvp_b = pv_b @ vp_w + vp_b
// oppo_w[128][128] = op_w @ po_w ; oppo_b = op_b @ po_w + po_b
__global__ void prep_weights(const float* __restrict__ pv_w, const float* __restrict__ pv_b,
                             const float* __restrict__ vp_w, const float* __restrict__ vp_b,
                             const float* __restrict__ op_w, const float* __restrict__ op_b,
                             const float* __restrict__ po_w, const float* __restrict__ po_b,
                             float* __restrict__ pvvp_w, float* __restrict__ pvvp_b,
                             float* __restrict__ oppo_w, float* __restrict__ oppo_b) {
    int r = blockIdx.x;
    int d = threadIdx.x; // 0..127
    if (r < 256) {
        float s = 0.f;
        for (int k = 0; k < 128; ++k) s += pv_w[r * 128 + k] * vp_w[k * 128 + d];
        pvvp_w[r * 128 + d] = s;
    } else if (r == 256) {
        float s = vp_b[d];
        for (int k = 0; k < 128; ++k) s += pv_b[k] * vp_w[k * 128 + d];
        pvvp_b[d] = s;
    } else if (r < 385) {
        int rr = r - 257;
        float s = 0.f;
        for (int k = 0; k < 128; ++k) s += op_w[rr * 128 + k] * po_w[k * 128 + d];
        oppo_w[rr * 128 + d] = s;
    } else {
        float s = po_b[d];
        for (int k = 0; k < 128; ++k) s += op_b[k] * po_w[k * 128 + d];
        oppo_b[d] = s;
    }
}

// ---------------- generic row-major GEMM ----------------
// C[M][ldc] = A[M][lda](cols 0..K-1) @ W[K][ldw](cols 0..NT-1) + bias
// emode 1: += sin(az_m)*extra_w[0][n] + cos(az_m)*extra_w[1][n]   (az from m&1023)
// emode 2: += extra2[2m]*extra_w[0][n] + extra2[2m+1]*extra_w[1][n]
// do_gelu: exact gelu applied after bias+extras
template <int MT, int NT, int NTH>
__global__ __launch_bounds__(NTH) void gemm_rn(
    const float* __restrict__ A, int lda,
    const float* __restrict__ W, int ldw,
    const float* __restrict__ bias,
    float* __restrict__ C, int ldc, int K,
    const float2* __restrict__ azsc,
    const float* __restrict__ extra2,
    const float* __restrict__ extra_w,
    int emode, int do_gelu) {
    static_assert(NTH == (MT / 4) * (NT / 4), "thread count mismatch");
    __shared__ float As[32][MT];
    __shared__ float Ws[32][NT];
    const int tid = threadIdx.x;
    constexpr int NTN = NT / 4;
    const int tn = tid % NTN;
    const int tm = tid / NTN;
    const int m0 = blockIdx.x * MT;
    float acc[4][4];
#pragma unroll
    for (int i = 0; i < 4; ++i)
#pragma unroll
        for (int j = 0; j < 4; ++j) acc[i][j] = 0.f;

    for (int k0 = 0; k0 < K; k0 += 32) {
        __syncthreads();
        // A tile: MT rows x 32 k, loaded as float4 along k, scattered to [k][m]
        for (int f = tid; f < MT * 8; f += NTH) {
            int r = f >> 3, c4 = f & 7;
            float4 v = *(const float4*)(A + (size_t)(m0 + r) * lda + k0 + c4 * 4);
            As[c4 * 4 + 0][r] = v.x;
            As[c4 * 4 + 1][r] = v.y;
            As[c4 * 4 + 2][r] = v.z;
            As[c4 * 4 + 3][r] = v.w;
        }
        // W chunk: 32 k x NT n
        for (int f = tid; f < 8 * NT; f += NTH) {
            int kk = f / NTN, n4 = f % NTN;
            float4 v = *(const float4*)(W + (size_t)(k0 + kk) * ldw + n4 * 4);
            *(float4*)&Ws[kk][n4 * 4] = v;
        }
        __syncthreads();
#pragma unroll
        for (int k = 0; k < 32; ++k) {
            const float4 av = *(const float4*)&As[k][tm * 4];
            const float4 wv = *(const float4*)&Ws[k][tn * 4];
            acc[0][0] += av.x * wv.x; acc[0][1] += av.x * wv.y; acc[0][2] += av.x * wv.z; acc[0][3] += av.x * wv.w;
            acc[1][0] += av.y * wv.x; acc[1][1] += av.y * wv.y; acc[1][2] += av.y * wv.z; acc[1][3] += av.y * wv.w;
            acc[2][0] += av.z * wv.x; acc[2][1] += av.z * wv.y; acc[2][2] += av.z * wv.z; acc[2][3] += av.z * wv.w;
            acc[3][0] += av.w * wv.x; acc[3][1] += av.w * wv.y; acc[3][2] += av.w * wv.z; acc[3][3] += av.w * wv.w;
        }
    }
#pragma unroll
    for (int i = 0; i < 4; ++i) {
        int m = m0 + tm * 4 + i;
        float e0 = 0.f, e1 = 0.f;
        if (emode == 1) {
            float2 sc = azsc[m & 1023];
            e0 = sc.x; e1 = sc.y;
        } else if (emode == 2) {
            e0 = extra2[2 * (size_t)m];
            e1 = extra2[2 * (size_t)m + 1];
        }
        float4 o;
        float* op_ = &o.x;
#pragma unroll
        for (int j = 0; j < 4; ++j) {
            int n = tn * 4 + j;
            float v = acc[i][j] + bias[n];
            if (emode) v += e0 * extra_w[n] + e1 * extra_w[ldw + n];
            if (do_gelu) v = gelu_f(v);
            op_[j] = v;
        }
        *(float4*)(C + (size_t)m * ldc + tn * 4) = o;
    }
}

// ---------------- value GEMM (A = bev^T strided) ----------------
// V[b][n][d] = sum_c bev[b][c][n] * Wf[c][d] + bf[d]   (c: 256, d: 128, n: 40000)
__global__ __launch_bounds__(256) void value_gemm(
    const float* __restrict__ bev, const float* __restrict__ Wf,
    const float* __restrict__ bf, float* __restrict__ V) {
    __shared__ float As[32][32];   // [k][n]
    __shared__ float Ws[32][128];  // [k][d]
    const int tid = threadIdx.x;
    const int tn = tid & 31, tm = tid >> 5;
    const int n0 = blockIdx.x * 32;
    const int b = blockIdx.y;
    const float* bevb = bev + (size_t)b * 256 * 40000;
    float acc[4][4];
#pragma unroll
    for (int i = 0; i < 4; ++i)
#pragma unroll
        for (int j = 0; j < 4; ++j) acc[i][j] = 0.f;

    for (int k0 = 0; k0 < 256; k0 += 32) {
        __syncthreads();
        for (int f = tid; f < 256; f += 256) {
            int kk = f >> 3, r4 = f & 7;
            float4 v = *(const float4*)(bevb + (size_t)(k0 + kk) * 40000 + n0 + r4 * 4);
            *(float4*)&As[kk][r4 * 4] = v;
        }
        for (int f = tid; f < 1024; f += 256) {
            int kk = f >> 5, n4 = f & 31;
            float4 v = *(const float4*)(Wf + (size_t)(k0 + kk) * 128 + n4 * 4);
            *(float4*)&Ws[kk][n4 * 4] = v;
        }
        __syncthreads();
#pragma unroll
        for (int k = 0; k < 32; ++k) {
            const float4 av = *(const float4*)&As[k][tm * 4];
            const float4 wv = *(const float4*)&Ws[k][tn * 4];
            acc[0][0] += av.x * wv.x; acc[0][1] += av.x * wv.y; acc[0][2] += av.x * wv.z; acc[0][3] += av.x * wv.w;
            acc[1][0] += av.y * wv.x; acc[1][1] += av.y * wv.y; acc[1][2] += av.y * wv.z; acc[1][3] += av.y * wv.w;
            acc[2][0] += av.z * wv.x; acc[2][1] += av.z * wv.y; acc[2][2] += av.z * wv.z; acc[2][3] += av.z * wv.w;
            acc[3][0] += av.w * wv.x; acc[3][1] += av.w * wv.y; acc[3][2] += av.w * wv.z; acc[3][3] += av.w * wv.w;
        }
    }
#pragma unroll
    for (int i = 0; i < 4; ++i) {
        float4 o;
        o.x = acc[i][0] + bf[tn * 4 + 0];
        o.y = acc[i][1] + bf[tn * 4 + 1];
        o.z = acc[i][2] + bf[tn * 4 + 2];
        o.w = acc[i][3] + bf[tn * 4 + 3];
        *(float4*)(V + ((size_t)b * 40000 + n0 + tm * 4 + i) * 128 + tn * 4) = o;
    }
}

// ---------------- GroupNorm stats ----------------
// X: [65536][C]; stats[(b*8+g)*2 + {0,1}] accumulates sum / sumsq (atomic)
template <int C, int CPG>
__global__ __launch_bounds__(256) void gn_stats(const float* __restrict__ X,
                                                float* __restrict__ stats) {
    const int tid = threadIdx.x;
    const int row0 = blockIdx.x * 512;
    const int b = row0 >> 15;
    const int c = tid & (C - 1);
    float s = 0.f, s2 = 0.f;
    const float* Xp = X + (size_t)row0 * C + tid;
    const int iters = 512 * C / 256;
    for (int j = 0; j < iters; ++j) {
        float v = Xp[(size_t)j * 256];
        s += v;
        s2 += v * v;
    }
    __shared__ float ss[256], sq[256];
    ss[tid] = s;
    sq[tid] = s2;
    __syncthreads();
    if (tid < 8) {
        float a = 0.f, a2 = 0.f;
        for (int t = 0; t < 256; ++t) {
            if (((t & (C - 1)) / CPG) == tid) { a += ss[t]; a2 += sq[t]; }
        }
        atomicAdd(&stats[(b * 8 + tid) * 2 + 0], a);
        atomicAdd(&stats[(b * 8 + tid) * 2 + 1], a2);
    }
    (void)c;
}

// ---------------- GroupNorm apply + GELU (in place) ----------------
template <int C, int CPG>
__global__ __launch_bounds__(256) void gn_apply(float* __restrict__ X,
                                                const float* __restrict__ stats,
                                                const float* __restrict__ gamma,
                                                const float* __restrict__ beta,
                                                float inv_cnt) {
    size_t i4 = (size_t)blockIdx.x * 256 + threadIdx.x;
    size_t base = i4 * 4;
    int c = (int)(base & (C - 1));
    int g = c / CPG;
    int m = (int)(base / C);
    int b = m >> 15;
    float mean = stats[(b * 8 + g) * 2 + 0] * inv_cnt;
    float var = stats[(b * 8 + g) * 2 + 1] * inv_cnt - mean * mean;
    float rs = 1.0f / sqrtf(var + 1e-5f);
    float4 x = *(const float4*)(X + base);
    float4 o;
    o.x = gelu_f((x.x - mean) * rs * gamma[c + 0] + beta[c + 0]);
    o.y = gelu_f((x.y - mean) * rs * gamma[c + 1] + beta[c + 1]);
    o.z = gelu_f((x.z - mean) * rs * gamma[c + 2] + beta[c + 2]);
    o.w = gelu_f((x.w - mean) * rs * gamma[c + 3] + beta[c + 3]);
    *(float4*)(X + base) = o;
}

// ---------------- 3x3 circular conv 128->64 ----------------
__global__ __launch_bounds__(256) void conv3x3_kernel(
    const float* __restrict__ X,   // [2][32][1024][128]
    const float* __restrict__ Wc,  // [3][3][128][64]
    float* __restrict__ Y) {       // [2][32][1024][64]
    __shared__ float in_s[3][32][66];  // [row][ci][x]
    __shared__ float w_s[32][64];      // [ci][o]
    const int tid = threadIdx.x;
    const int xl = tid & 63;
    const int og = tid >> 6;  // 0..3 -> o = og*16 + j
    const int x0 = blockIdx.x * 64;
    const int y = blockIdx.y;
    const int b = blockIdx.z;
    const float* Xb = X + (size_t)b * 32 * 1024 * 128;
    float acc[16];
#pragma unroll
    for (int j = 0; j < 16; ++j) acc[j] = 0.f;

    for (int cc = 0; cc < 128; cc += 32) {
        __syncthreads();
        // 3 rows x 66 x-positions x 32 channels = 1584 float4
        for (int f = tid; f < 1584; f += 256) {
            int ry = f / 528;
            int rem = f - ry * 528;
            int xx = rem >> 3;
            int c4 = rem & 7;
            int gy = (y + ry + 31) & 31;
            int gx = (x0 + xx + 1023) & 1023;
            float4 v = *(const float4*)(Xb + ((size_t)gy * 1024 + gx) * 128 + cc + c4 * 4);
            in_s[ry][c4 * 4 + 0][xx] = v.x;
            in_s[ry][c4 * 4 + 1][xx] = v.y;
            in_s[ry][c4 * 4 + 2][xx] = v.z;
            in_s[ry][c4 * 4 + 3][xx] = v.w;
        }
        for (int tap = 0; tap < 9; ++tap) {
            const int dy = tap / 3, dx = tap - dy * 3;
            __syncthreads();
            for (int f = tid; f < 512; f += 256) {
                int ci = f >> 4, o4 = f & 15;
                float4 v = *(const float4*)(Wc + ((size_t)tap * 128 + cc + ci) * 64 + o4 * 4);
                *(float4*)&w_s[ci][o4 * 4] = v;
            }
            __syncthreads();
            const float* ip = &in_s[dy][0][xl + dx];
            const float4* wp = (const float4*)&w_s[0][og * 16];
#pragma unroll 8
            for (int ci = 0; ci < 32; ++ci) {
                float a = ip[ci * 66];
                float4 w0 = wp[ci * 16 + 0];
                float4 w1 = wp[ci * 16 + 1];
                float4 w2 = wp[ci * 16 + 2];
                float4 w3 = wp[ci * 16 + 3];
                acc[0] += a * w0.x; acc[1] += a * w0.y; acc[2] += a * w0.z; acc[3] += a * w0.w;
                acc[4] += a * w1.x; acc[5] += a * w1.y; acc[6] += a * w1.z; acc[7] += a * w1.w;
                acc[8] += a * w2.x; acc[9] += a * w2.y; acc[10] += a * w2.z; acc[11] += a * w2.w;
                acc[12] += a * w3.x; acc[13] += a * w3.y; acc[14] += a * w3.z; acc[15] += a * w3.w;
            }
        }
    }
    float* yp = Y + (((size_t)(b * 32 + y) * 1024 + x0 + xl) * 64 + og * 16);
    *(float4*)(yp + 0) = make_float4(acc[0], acc[1], acc[2], acc[3]);
    *(float4*)(yp + 4) = make_float4(acc[4], acc[5], acc[6], acc[7]);
    *(float4*)(yp + 8) = make_float4(acc[8], acc[9], acc[10], acc[11]);
    *(float4*)(yp + 12) = make_float4(acc[12], acc[13], acc[14], acc[15]);
}

// ---------------- range-head output -> ref / sig_feat ----------------
__global__ __launch_bounds__(256) void rh3_kernel(
    const float* __restrict__ H2,  // [65536][64]
    const float* __restrict__ w3,  // [64][2]
    const float* __restrict__ b3,  // [2]
    const float2* __restrict__ azsc,
    float2* __restrict__ refxy, float2* __restrict__ sigf) {
    const int tid = threadIdx.x;
    const int lane = tid & 15;
    const int m = blockIdx.x * 16 + (tid >> 4);
    float4 v = *(const float4*)(H2 + (size_t)m * 64 + lane * 4);
    float d0 = 0.f, d1 = 0.f;
    const float* hv = &v.x;
#pragma unroll
    for (int k = 0; k < 4; ++k) {
        d0 += hv[k] * w3[(lane * 4 + k) * 2 + 0];
        d1 += hv[k] * w3[(lane * 4 + k) * 2 + 1];
    }
#pragma unroll
    for (int s = 1; s < 16; s <<= 1) {
        d0 += __shfl_xor(d0, s, 16);
        d1 += __shfl_xor(d1, s, 16);
    }
    if (lane == 0) {
        float mu = fminf(fmaxf(d0 + b3[0], 0.f), 55.f);
        float ls = fminf(fmaxf(d1 + b3[1], -5.f), 3.f);
        float sg = expf(ls);
        float2 sc = azsc[m & 1023];
        float x_mu = mu * sc.y;  // cos
        float y_mu = mu * sc.x;  // sin
        float rx = fminf(fmaxf(x_mu * 0.01f + 0.5f, 0.f), 1.f);
        float ry = fminf(fmaxf(y_mu * 0.01f + 0.5f, 0.f), 1.f);
        refxy[m] = make_float2(rx, ry);
        sigf[m] = make_float2(ls, 1.f / (sg + 1e-6f));
    }
}

// ---------------- MSDA bilinear sampling ----------------
__device__ __forceinline__ float samp_v(const float* __restrict__ Vb, int x, int y) {
    bool valid = ((unsigned)x < 200u) && ((unsigned)y < 200u);
    int xc = min(max(x, 0), 199);
    int yc = min(max(y, 0), 199);
    float v = Vb[((size_t)yc * 200 + xc) * 128];
    return valid ? v : 0.f;
}

__global__ __launch_bounds__(256) void msda_kernel(
    const float* __restrict__ V,       // [2][40000][128]
    const float2* __restrict__ refxy,  // [65536]
    const float* __restrict__ offs,    // [65536][96]
    const float* __restrict__ aw,      // [65536][48]
    float* __restrict__ out) {         // [65536][128]
    const int tid = threadIdx.x;
    const int lane = tid & 15;
    const int grp = tid >> 4;
    const int m = blockIdx.x * 2 + (grp >> 3);
    const int head = grp & 7;
    const int b = m >> 15;
    float2 r = refxy[m];
    const float* lg = aw + (size_t)m * 48 + head * 6;
    float l[6];
#pragma unroll
    for (int p = 0; p < 6; ++p) l[p] = lg[p];
    float mx = l[0];
#pragma unroll
    for (int p = 1; p < 6; ++p) mx = fmaxf(mx, l[p]);
    float s = 0.f;
#pragma unroll
    for (int p = 0; p < 6; ++p) { l[p] = expf(l[p] - mx); s += l[p]; }
    float inv = 1.f / s;
    const float* of = offs + (size_t)m * 96 + head * 12;
    const float* Vb = V + (size_t)b * 40000 * 128 + head * 16 + lane;
    float acc = 0.f;
#pragma unroll
    for (int p = 0; p < 6; ++p) {
        float px = r.x * 200.f + of[p * 2 + 0] - 0.5f;
        float py = r.y * 200.f + of[p * 2 + 1] - 0.5f;
        float fx = floorf(px), fy = floorf(py);
        int x0 = (int)fx, y0 = (int)fy;
        float wx = px - fx, wy = py - fy;
        float v00 = samp_v(Vb, x0, y0);
        float v10 = samp_v(Vb, x0 + 1, y0);
        float v01 = samp_v(Vb, x0, y0 + 1);
        float v11 = samp_v(Vb, x0 + 1, y0 + 1);
        float bil = v00 * (1.f - wx) * (1.f - wy) + v10 * wx * (1.f - wy) +
                    v01 * (1.f - wx) * wy + v11 * wx * wy;
        acc += l[p] * inv * bil;
    }
    out[(size_t)m * 128 + head * 16 + lane] = acc;
}

// ---------------- launch ----------------
extern "C" void kernel_launch(void* const* d_in, const int* in_sizes, int n_in,
                              void* d_out, int out_size, void* d_ws, size_t ws_size,
                              hipStream_t stream) {
    const float* x_rv = (const float*)d_in[0];
    const float* bev = (const float*)d_in[1];
    const float* pq_w = (const float*)d_in[2];
    const float* pq_b = (const float*)d_in[3];
    const float* pv_w = (const float*)d_in[4];
    const float* pv_b = (const float*)d_in[5];
    const float* po_w = (const float*)d_in[6];
    const float* po_b = (const float*)d_in[7];
    const float* qs_w1 = (const float*)d_in[8];
    const float* qs_b1 = (const float*)d_in[9];
    const float* qs_w2 = (const float*)d_in[10];
    const float* qs_b2 = (const float*)d_in[11];
    const float* rh_w1 = (const float*)d_in[12];
    const float* rh_b1 = (const float*)d_in[13];
    const float* rh_g1 = (const float*)d_in[14];
    const float* rh_be1 = (const float*)d_in[15];
    const float* rh_w2 = (const float*)d_in[16];
    const float* rh_g2 = (const float*)d_in[17];
    const float* rh_be2 = (const float*)d_in[18];
    const float* rh_w3 = (const float*)d_in[19];
    const float* rh_b3 = (const float*)d_in[20];
    const float* so_w = (const float*)d_in[21];
    const float* so_b = (const float*)d_in[22];
    const float* aw_w = (const float*)d_in[23];
    const float* aw_b = (const float*)d_in[24];
    const float* vp_w = (const float*)d_in[25];
    const float* vp_b = (const float*)d_in[26];
    const float* op_w = (const float*)d_in[27];
    const float* op_b = (const float*)d_in[28];

    const int M = 65536;  // B*HRV*WRV

    float* ws = (float*)d_ws;
    float* azsc = ws;           ws += 2048;        // float2[1024]
    float* pvvp_w = ws;         ws += 256 * 128;
    float* pvvp_b = ws;         ws += 128;
    float* oppo_w = ws;         ws += 128 * 128;
    float* oppo_b = ws;         ws += 128;
    float* stats = ws;          ws += 32;
    ws += 32;  // pad
    float* Q0 = ws;             ws += (size_t)M * 128;
    float* Vv = ws;             ws += (size_t)80000 * 128;
    float* h1 = ws;             ws += (size_t)M * 128;
    float* h2 = ws;             ws += (size_t)M * 64;
    float* q1 = ws;             ws += (size_t)M * 128;
    float* mo = ws;             ws += (size_t)M * 128;
    float* refxy = ws;          ws += (size_t)M * 2;
    float* sigf = ws;           ws += (size_t)M * 2;
    size_t need_bytes = (size_t)(ws - (float*)d_ws) * sizeof(float);
    if (ws_size < need_bytes) return;  // workspace too small; fail visibly via absmax
    float* query = h1;  // h1 dead after conv
    float* offs = q1;   // q1 dead after qs2
    float* attw = Q0;   // Q0 dead after qs1

    float2* azsc2 = (float2*)azsc;
    float2* refxy2 = (float2*)refxy;
    float2* sigf2 = (float2*)sigf;

    azsc_kernel<<<4, 256, 0, stream>>>(azsc2);
    prep_weights<<<386, 128, 0, stream>>>(pv_w, pv_b, vp_w, vp_b, op_w, op_b, po_w, po_b,
                                          pvvp_w, pvvp_b, oppo_w, oppo_b);

    // Q0 = x_rv @ pq_w + pq_b
    gemm_rn<32, 128, 256><<<M / 32, 256, 0, stream>>>(
        x_rv, 64, pq_w, 128, pq_b, Q0, 128, 64, nullptr, nullptr, nullptr, 0, 0);

    // value = bev^T @ (pv_w@vp_w) + fused bias
    value_gemm<<<dim3(1250, 2), 256, 0, stream>>>(bev, pvvp_w, pvvp_b, Vv);

    // h1 = concat(x_rv, [sin,cos,0]) @ rh_w1 + rh_b1
    gemm_rn<32, 128, 256><<<M / 32, 256, 0, stream>>>(
        x_rv, 64, rh_w1, 128, rh_b1, h1, 128, 64, azsc2, nullptr, rh_w1 + 64 * 128, 1, 0);

    // GN1 + gelu (in place)
    hipMemsetAsync(stats, 0, 32 * sizeof(float), stream);
    gn_stats<128, 16><<<128, 256, 0, stream>>>(h1, stats);
    gn_apply<128, 16><<<8192, 256, 0, stream>>>(h1, stats, rh_g1, rh_be1, 1.0f / 524288.0f);

    // 3x3 circular conv 128 -> 64
    conv3x3_kernel<<<dim3(16, 32, 2), 256, 0, stream>>>(h1, rh_w2, h2);

    // GN2 + gelu (in place)
    hipMemsetAsync(stats, 0, 32 * sizeof(float), stream);
    gn_stats<64, 8><<<128, 256, 0, stream>>>(h2, stats);
    gn_apply<64, 8><<<4096, 256, 0, stream>>>(h2, stats, rh_g2, rh_be2, 1.0f / 262144.0f);

    // rh3 -> refxy, sig_feat
    rh3_kernel<<<4096, 256, 0, stream>>>(h2, rh_w3, rh_b3, azsc2, refxy2, sigf2);

    // q1 = gelu(concat(Q0, sig_feat) @ qs_w1 + qs_b1)
    gemm_rn<32, 128, 256><<<M / 32, 256, 0, stream>>>(
        Q0, 128, qs_w1, 128, qs_b1, q1, 128, 128, nullptr, sigf, qs_w1 + 128 * 128, 2, 1);

    // query = q1 @ qs_w2 + qs_b2  (into h1)
    gemm_rn<32, 128, 256><<<M / 32, 256, 0, stream>>>(
        q1, 128, qs_w2, 128, qs_b2, query, 128, 128, nullptr, nullptr, nullptr, 0, 0);

    // offs = query @ so_w + so_b  (into q1)
    gemm_rn<32, 96, 192><<<M / 32, 192, 0, stream>>>(
        query, 128, so_w, 96, so_b, offs, 96, 128, nullptr, nullptr, nullptr, 0, 0);

    // attw logits = query @ aw_w + aw_b  (into Q0)
    gemm_rn<64, 48, 192><<<M / 64, 192, 0, stream>>>(
        query, 128, aw_w, 48, aw_b, attw, 48, 128, nullptr, nullptr, nullptr, 0, 0);

    // MSDA sampling
    msda_kernel<<<M / 2, 256, 0, stream>>>(Vv, refxy2, offs, attw, mo);

    // y = mo @ (op_w@po_w) + fused bias  -> d_out
    gemm_rn<32, 128, 256><<<M / 32, 256, 0, stream>>>(
        mo, 128, oppo_w, 128, oppo_b, (float*)d_out, 128, 128, nullptr, nullptr, nullptr, 0, 0);
}

// Round 2
// 795.018 us; speedup vs baseline: 1.0251x; 1.0251x over previous
//
#include <hip/hip_runtime.h>
#include <math.h>

#define PI_F 3.14159265358979323846f

// ---- static config ----
// B=2, HRV=32, WRV=1024, CRV=64; CB=256, HB=200, WB=200
// D=128, COUT=128, HEADS=8, POINTS=6, DH=16
// M = B*HRV*WRV = 65536 rows, NV = HB*WB = 40000

__device__ __forceinline__ float gelu_f(float x) {
    return 0.5f * x * (1.0f + erff(x * 0.70710678118654752440f));
}

// ---------------- az sin/cos table ----------------
__global__ void azsc_kernel(float2* __restrict__ azsc) {
    int w = blockIdx.x * 256 + threadIdx.x;
    if (w < 1024) {
        float az = -PI_F + (float)w * (6.283185307179586f / 1024.0f);
        azsc[w] = make_float2(sinf(az), cosf(az));
    }
}

// ---------------- fused weight prep ----------------
// pvvp_w[256][128] = pv_w @ vp_w ; pvvp_b = pv_b @ vp_w + vp_b
// oppo_w[128][128] = op_w @ po_w ; oppo_b = op_b @ po_w + po_b
// pqqs_w[64][128]  = pq_w @ qs_w1[:128] ; pqqs_b = pq_b @ qs_w1[:128] + qs_b1
__global__ void prep_weights(const float* __restrict__ pv_w, const float* __restrict__ pv_b,
                             const float* __restrict__ vp_w, const float* __restrict__ vp_b,
                             const float* __restrict__ op_w, const float* __restrict__ op_b,
                             const float* __restrict__ po_w, const float* __restrict__ po_b,
                             const float* __restrict__ pq_w, const float* __restrict__ pq_b,
                             const float* __restrict__ qs_w1, const float* __restrict__ qs_b1,
                             float* __restrict__ pvvp_w, float* __restrict__ pvvp_b,
                             float* __restrict__ oppo_w, float* __restrict__ oppo_b,
                             float* __restrict__ pqqs_w, float* __restrict__ pqqs_b) {
    int r = blockIdx.x;
    int d = threadIdx.x; // 0..127
    if (r < 256) {
        float s = 0.f;
        for (int k = 0; k < 128; ++k) s += pv_w[r * 128 + k] * vp_w[k * 128 + d];
        pvvp_w[r * 128 + d] = s;
    } else if (r == 256) {
        float s = vp_b[d];
        for (int k = 0; k < 128; ++k) s += pv_b[k] * vp_w[k * 128 + d];
        pvvp_b[d] = s;
    } else if (r < 385) {
        int rr = r - 257;
        float s = 0.f;
        for (int k = 0; k < 128; ++k) s += op_w[rr * 128 + k] * po_w[k * 128 + d];
        oppo_w[rr * 128 + d] = s;
    } else if (r == 385) {
        float s = po_b[d];
        for (int k = 0; k < 128; ++k) s += op_b[k] * po_w[k * 128 + d];
        oppo_b[d] = s;
    } else if (r < 450) {
        int rr = r - 386;
        float s = 0.f;
        for (int k = 0; k < 128; ++k) s += pq_w[rr * 128 + k] * qs_w1[k * 128 + d];
        pqqs_w[rr * 128 + d] = s;
    } else {
        float s = qs_b1[d];
        for (int k = 0; k < 128; ++k) s += pq_b[k] * qs_w1[k * 128 + d];
        pqqs_b[d] = s;
    }
}

// ---------------- generic row-major GEMM (8x4 micro-tile) ----------------
// C[M][ldc] = A[M][lda](cols 0..K-1) @ W[K][ldw](cols 0..NT-1) + bias
// emode 1: += sin(az_m)*extra_w[0][n] + cos(az_m)*extra_w[1][n]
// emode 2: += extra2[2m]*extra_w[0][n] + extra2[2m+1]*extra_w[1][n]
template <int MT, int NT, int NTH>
__global__ __launch_bounds__(NTH) void gemm_rn(
    const float* __restrict__ A, int lda,
    const float* __restrict__ W, int ldw,
    const float* __restrict__ bias,
    float* __restrict__ C, int ldc, int K,
    const float2* __restrict__ azsc,
    const float* __restrict__ extra2,
    const float* __restrict__ extra_w,
    int emode, int do_gelu) {
    static_assert(NTH == (MT / 8) * (NT / 4), "thread count mismatch");
    __shared__ float As[32][MT + 4];  // +4 pad: keeps b128 alignment, cuts scatter conflicts
    __shared__ float Ws[32][NT];
    constexpr int NTN = NT / 4;
    const int tid = threadIdx.x;
    const int tn = tid % NTN;
    const int tm = tid / NTN;
    const int m0 = blockIdx.x * MT;
    float acc[8][4];
#pragma unroll
    for (int i = 0; i < 8; ++i)
#pragma unroll
        for (int j = 0; j < 4; ++j) acc[i][j] = 0.f;

    for (int k0 = 0; k0 < K; k0 += 32) {
        __syncthreads();
        // A tile: MT rows x 32 k, float4 along k, scattered to [k][m]
        for (int f = tid; f < MT * 8; f += NTH) {
            int r = f >> 3, c4 = f & 7;
            float4 v = *(const float4*)(A + (size_t)(m0 + r) * lda + k0 + c4 * 4);
            As[c4 * 4 + 0][r] = v.x;
            As[c4 * 4 + 1][r] = v.y;
            As[c4 * 4 + 2][r] = v.z;
            As[c4 * 4 + 3][r] = v.w;
        }
        // W chunk: 32 k x NT n
        for (int f = tid; f < 8 * NT; f += NTH) {
            int kk = f / NTN, n4 = f % NTN;
            *(float4*)&Ws[kk][n4 * 4] = *(const float4*)(W + (size_t)(k0 + kk) * ldw + n4 * 4);
        }
        __syncthreads();
#pragma unroll
        for (int k = 0; k < 32; ++k) {
            const float4 a0 = *(const float4*)&As[k][tm * 8];
            const float4 a1 = *(const float4*)&As[k][tm * 8 + 4];
            const float4 wv = *(const float4*)&Ws[k][tn * 4];
            acc[0][0] += a0.x * wv.x; acc[0][1] += a0.x * wv.y; acc[0][2] += a0.x * wv.z; acc[0][3] += a0.x * wv.w;
            acc[1][0] += a0.y * wv.x; acc[1][1] += a0.y * wv.y; acc[1][2] += a0.y * wv.z; acc[1][3] += a0.y * wv.w;
            acc[2][0] += a0.z * wv.x; acc[2][1] += a0.z * wv.y; acc[2][2] += a0.z * wv.z; acc[2][3] += a0.z * wv.w;
            acc[3][0] += a0.w * wv.x; acc[3][1] += a0.w * wv.y; acc[3][2] += a0.w * wv.z; acc[3][3] += a0.w * wv.w;
            acc[4][0] += a1.x * wv.x; acc[4][1] += a1.x * wv.y; acc[4][2] += a1.x * wv.z; acc[4][3] += a1.x * wv.w;
            acc[5][0] += a1.y * wv.x; acc[5][1] += a1.y * wv.y; acc[5][2] += a1.y * wv.z; acc[5][3] += a1.y * wv.w;
            acc[6][0] += a1.z * wv.x; acc[6][1] += a1.z * wv.y; acc[6][2] += a1.z * wv.z; acc[6][3] += a1.z * wv.w;
            acc[7][0] += a1.w * wv.x; acc[7][1] += a1.w * wv.y; acc[7][2] += a1.w * wv.z; acc[7][3] += a1.w * wv.w;
        }
    }
#pragma unroll
    for (int i = 0; i < 8; ++i) {
        int m = m0 + tm * 8 + i;
        float e0 = 0.f, e1 = 0.f;
        if (emode == 1) {
            float2 sc = azsc[m & 1023];
            e0 = sc.x; e1 = sc.y;
        } else if (emode == 2) {
            e0 = extra2[2 * (size_t)m];
            e1 = extra2[2 * (size_t)m + 1];
        }
        float4 o;
        float* op_ = &o.x;
#pragma unroll
        for (int j = 0; j < 4; ++j) {
            int n = tn * 4 + j;
            float v = acc[i][j] + bias[n];
            if (emode) v += e0 * extra_w[n] + e1 * extra_w[ldw + n];
            if (do_gelu) v = gelu_f(v);
            op_[j] = v;
        }
        *(float4*)(C + (size_t)m * ldc + tn * 4) = o;
    }
}

// ---------------- value GEMM (A = bev^T strided), 64-col tile ----------------
// V[b][n][d] = sum_c bev[b][c][n] * Wf[c][d] + bf[d]
__global__ __launch_bounds__(256) void value_gemm(
    const float* __restrict__ bev, const float* __restrict__ Wf,
    const float* __restrict__ bf, float* __restrict__ V) {
    __shared__ float As[32][64];   // [k][n] (natural layout, no transpose)
    __shared__ float Ws[32][128];  // [k][d]
    const int tid = threadIdx.x;
    const int tn = tid & 31, tm = tid >> 5;  // tm 0..7 -> 8 n-rows each
    const int n0 = blockIdx.x * 64;
    const int b = blockIdx.y;
    const float* bevb = bev + (size_t)b * 256 * 40000;
    float acc[8][4];
#pragma unroll
    for (int i = 0; i < 8; ++i)
#pragma unroll
        for (int j = 0; j < 4; ++j) acc[i][j] = 0.f;

    for (int k0 = 0; k0 < 256; k0 += 32) {
        __syncthreads();
        for (int f = tid; f < 512; f += 256) {
            int kk = f >> 4, n4 = f & 15;
            *(float4*)&As[kk][n4 * 4] =
                *(const float4*)(bevb + (size_t)(k0 + kk) * 40000 + n0 + n4 * 4);
        }
        for (int f = tid; f < 1024; f += 256) {
            int kk = f >> 5, n4 = f & 31;
            *(float4*)&Ws[kk][n4 * 4] = *(const float4*)(Wf + (size_t)(k0 + kk) * 128 + n4 * 4);
        }
        __syncthreads();
#pragma unroll
        for (int k = 0; k < 32; ++k) {
            const float4 a0 = *(const float4*)&As[k][tm * 8];
            const float4 a1 = *(const float4*)&As[k][tm * 8 + 4];
            const float4 wv = *(const float4*)&Ws[k][tn * 4];
            acc[0][0] += a0.x * wv.x; acc[0][1] += a0.x * wv.y; acc[0][2] += a0.x * wv.z; acc[0][3] += a0.x * wv.w;
            acc[1][0] += a0.y * wv.x; acc[1][1] += a0.y * wv.y; acc[1][2] += a0.y * wv.z; acc[1][3] += a0.y * wv.w;
            acc[2][0] += a0.z * wv.x; acc[2][1] += a0.z * wv.y; acc[2][2] += a0.z * wv.z; acc[2][3] += a0.z * wv.w;
            acc[3][0] += a0.w * wv.x; acc[3][1] += a0.w * wv.y; acc[3][2] += a0.w * wv.z; acc[3][3] += a0.w * wv.w;
            acc[4][0] += a1.x * wv.x; acc[4][1] += a1.x * wv.y; acc[4][2] += a1.x * wv.z; acc[4][3] += a1.x * wv.w;
            acc[5][0] += a1.y * wv.x; acc[5][1] += a1.y * wv.y; acc[5][2] += a1.y * wv.z; acc[5][3] += a1.y * wv.w;
            acc[6][0] += a1.z * wv.x; acc[6][1] += a1.z * wv.y; acc[6][2] += a1.z * wv.z; acc[6][3] += a1.z * wv.w;
            acc[7][0] += a1.w * wv.x; acc[7][1] += a1.w * wv.y; acc[7][2] += a1.w * wv.z; acc[7][3] += a1.w * wv.w;
        }
    }
#pragma unroll
    for (int i = 0; i < 8; ++i) {
        float4 o;
        o.x = acc[i][0] + bf[tn * 4 + 0];
        o.y = acc[i][1] + bf[tn * 4 + 1];
        o.z = acc[i][2] + bf[tn * 4 + 2];
        o.w = acc[i][3] + bf[tn * 4 + 3];
        *(float4*)(V + ((size_t)b * 40000 + n0 + tm * 8 + i) * 128 + tn * 4) = o;
    }
}

// ---------------- GroupNorm stats ----------------
template <int C, int CPG, int ROWS>
__global__ __launch_bounds__(256) void gn_stats(const float* __restrict__ X,
                                                float* __restrict__ stats) {
    const int tid = threadIdx.x;
    const int row0 = blockIdx.x * ROWS;
    const int b = row0 >> 15;
    float s = 0.f, s2 = 0.f;
    const float* Xp = X + (size_t)row0 * C + tid;
    const int iters = ROWS * C / 256;
    for (int j = 0; j < iters; ++j) {
        float v = Xp[(size_t)j * 256];
        s += v;
        s2 += v * v;
    }
    __shared__ float ss[256], sq[256];
    ss[tid] = s;
    sq[tid] = s2;
    __syncthreads();
    if (tid < 8) {
        float a = 0.f, a2 = 0.f;
        for (int t = 0; t < 256; ++t) {
            if (((t & (C - 1)) / CPG) == tid) { a += ss[t]; a2 += sq[t]; }
        }
        atomicAdd(&stats[(b * 8 + tid) * 2 + 0], a);
        atomicAdd(&stats[(b * 8 + tid) * 2 + 1], a2);
    }
}

// ---------------- GroupNorm apply + GELU (in place) ----------------
template <int C, int CPG>
__global__ __launch_bounds__(256) void gn_apply(float* __restrict__ X,
                                                const float* __restrict__ stats,
                                                const float* __restrict__ gamma,
                                                const float* __restrict__ beta,
                                                float inv_cnt) {
    size_t i4 = (size_t)blockIdx.x * 256 + threadIdx.x;
    size_t base = i4 * 4;
    int c = (int)(base & (C - 1));
    int g = c / CPG;
    int m = (int)(base / C);
    int b = m >> 15;
    float mean = stats[(b * 8 + g) * 2 + 0] * inv_cnt;
    float var = stats[(b * 8 + g) * 2 + 1] * inv_cnt - mean * mean;
    float rs = 1.0f / sqrtf(var + 1e-5f);
    float4 x = *(const float4*)(X + base);
    float4 o;
    o.x = gelu_f((x.x - mean) * rs * gamma[c + 0] + beta[c + 0]);
    o.y = gelu_f((x.y - mean) * rs * gamma[c + 1] + beta[c + 1]);
    o.z = gelu_f((x.z - mean) * rs * gamma[c + 2] + beta[c + 2]);
    o.w = gelu_f((x.w - mean) * rs * gamma[c + 3] + beta[c + 3]);
    *(float4*)(X + base) = o;
}

// ---------------- 3x3 circular conv 128->64 ----------------
// cc-chunk = 8 with ALL 9 taps' weights staged at once: 32 barriers/block
// (was 72), 1152 FMA between barriers. LDS 24.8 KB -> 4 blocks/CU (grid-capped).
__global__ __launch_bounds__(256) void conv3x3_kernel(
    const float* __restrict__ X,   // [2][32][1024][128]
    const float* __restrict__ Wc,  // [3][3][128][64]
    float* __restrict__ Y) {       // [2][32][1024][64]
    __shared__ float in_s[3][8][66];  // [row][ci][x]
    __shared__ float w_s[9][8][64];   // [tap][ci][o]
    const int tid = threadIdx.x;
    const int xl = tid & 63;
    const int og = tid >> 6;  // 0..3 -> o = og*16 + j
    const int x0 = blockIdx.x * 64;
    const int y = blockIdx.y;
    const int b = blockIdx.z;
    const float* Xb = X + (size_t)b * 32 * 1024 * 128;
    float acc[16];
#pragma unroll
    for (int j = 0; j < 16; ++j) acc[j] = 0.f;

    for (int cc = 0; cc < 128; cc += 8) {
        __syncthreads();
        // input: 3 rows x 66 x x 2 float4 (8 ci) = 396 float4
        for (int f = tid; f < 396; f += 256) {
            int c4 = f & 1;
            int xx = (f >> 1) % 66;
            int ry = f / 132;
            int gy = (y + ry + 31) & 31;
            int gx = (x0 + xx + 1023) & 1023;
            float4 v = *(const float4*)(Xb + ((size_t)gy * 1024 + gx) * 128 + cc + c4 * 4);
            in_s[ry][c4 * 4 + 0][xx] = v.x;
            in_s[ry][c4 * 4 + 1][xx] = v.y;
            in_s[ry][c4 * 4 + 2][xx] = v.z;
            in_s[ry][c4 * 4 + 3][xx] = v.w;
        }
        // weights: 9 taps x 8 ci x 16 float4 = 1152 float4
        for (int f = tid; f < 1152; f += 256) {
            int o4 = f & 15;
            int ci = (f >> 4) & 7;
            int tap = f >> 7;
            *(float4*)&w_s[tap][ci][o4 * 4] =
                *(const float4*)(Wc + ((size_t)tap * 128 + cc + ci) * 64 + o4 * 4);
        }
        __syncthreads();
#pragma unroll
        for (int tap = 0; tap < 9; ++tap) {
            const int dy = tap / 3, dx = tap % 3;
            const float* ip = &in_s[dy][0][xl + dx];
            const float4* wp = (const float4*)&w_s[tap][0][og * 16];
#pragma unroll
            for (int ci = 0; ci < 8; ++ci) {
                float a = ip[ci * 66];
                float4 w0 = wp[ci * 16 + 0];
                float4 w1 = wp[ci * 16 + 1];
                float4 w2 = wp[ci * 16 + 2];
                float4 w3 = wp[ci * 16 + 3];
                acc[0] += a * w0.x; acc[1] += a * w0.y; acc[2] += a * w0.z; acc[3] += a * w0.w;
                acc[4] += a * w1.x; acc[5] += a * w1.y; acc[6] += a * w1.z; acc[7] += a * w1.w;
                acc[8] += a * w2.x; acc[9] += a * w2.y; acc[10] += a * w2.z; acc[11] += a * w2.w;
                acc[12] += a * w3.x; acc[13] += a * w3.y; acc[14] += a * w3.z; acc[15] += a * w3.w;
            }
        }
    }
    float* yp = Y + (((size_t)(b * 32 + y) * 1024 + x0 + xl) * 64 + og * 16);
    *(float4*)(yp + 0) = make_float4(acc[0], acc[1], acc[2], acc[3]);
    *(float4*)(yp + 4) = make_float4(acc[4], acc[5], acc[6], acc[7]);
    *(float4*)(yp + 8) = make_float4(acc[8], acc[9], acc[10], acc[11]);
    *(float4*)(yp + 12) = make_float4(acc[12], acc[13], acc[14], acc[15]);
}

// ---------------- fused GN2-apply + GELU + rh3 head ----------------
__global__ __launch_bounds__(256) void rh3_kernel(
    const float* __restrict__ H2,  // [65536][64] UN-normalized conv output
    const float* __restrict__ stats, const float* __restrict__ gamma,
    const float* __restrict__ beta, float inv_cnt,
    const float* __restrict__ w3,  // [64][2]
    const float* __restrict__ b3,  // [2]
    const float2* __restrict__ azsc,
    float2* __restrict__ refxy, float2* __restrict__ sigf) {
    const int tid = threadIdx.x;
    const int lane = tid & 15;
    const int m = blockIdx.x * 16 + (tid >> 4);
    const int b = m >> 15;
    const int c = lane * 4;
    const int g = c >> 3;  // CPG=8; c..c+3 stay within one group
    float mean = stats[(b * 8 + g) * 2 + 0] * inv_cnt;
    float var = stats[(b * 8 + g) * 2 + 1] * inv_cnt - mean * mean;
    float rs = 1.0f / sqrtf(var + 1e-5f);
    float4 v = *(const float4*)(H2 + (size_t)m * 64 + c);
    float hv[4];
    hv[0] = gelu_f((v.x - mean) * rs * gamma[c + 0] + beta[c + 0]);
    hv[1] = gelu_f((v.y - mean) * rs * gamma[c + 1] + beta[c + 1]);
    hv[2] = gelu_f((v.z - mean) * rs * gamma[c + 2] + beta[c + 2]);
    hv[3] = gelu_f((v.w - mean) * rs * gamma[c + 3] + beta[c + 3]);
    float d0 = 0.f, d1 = 0.f;
#pragma unroll
    for (int k = 0; k < 4; ++k) {
        d0 += hv[k] * w3[(c + k) * 2 + 0];
        d1 += hv[k] * w3[(c + k) * 2 + 1];
    }
#pragma unroll
    for (int s = 1; s < 16; s <<= 1) {
        d0 += __shfl_xor(d0, s, 16);
        d1 += __shfl_xor(d1, s, 16);
    }
    if (lane == 0) {
        float mu = fminf(fmaxf(d0 + b3[0], 0.f), 55.f);
        float ls = fminf(fmaxf(d1 + b3[1], -5.f), 3.f);
        float sg = expf(ls);
        float2 sc = azsc[m & 1023];
        float x_mu = mu * sc.y;  // cos
        float y_mu = mu * sc.x;  // sin
        float rx = fminf(fmaxf(x_mu * 0.01f + 0.5f, 0.f), 1.f);
        float ry = fminf(fmaxf(y_mu * 0.01f + 0.5f, 0.f), 1.f);
        refxy[m] = make_float2(rx, ry);
        sigf[m] = make_float2(ls, 1.f / (sg + 1e-6f));
    }
}

// ---------------- MSDA bilinear sampling ----------------
__device__ __forceinline__ float samp_v(const float* __restrict__ Vb, int x, int y) {
    bool valid = ((unsigned)x < 200u) && ((unsigned)y < 200u);
    int xc = min(max(x, 0), 199);
    int yc = min(max(y, 0), 199);
    float v = Vb[((size_t)yc * 200 + xc) * 128];
    return valid ? v : 0.f;
}

__global__ __launch_bounds__(256) void msda_kernel(
    const float* __restrict__ V,       // [2][40000][128]
    const float2* __restrict__ refxy,  // [65536]
    const float* __restrict__ offs,    // [65536][96]
    const float* __restrict__ aw,      // [65536][48]
    float* __restrict__ out) {         // [65536][128]
    const int tid = threadIdx.x;
    const int lane = tid & 15;
    const int grp = tid >> 4;
    const int m = blockIdx.x * 2 + (grp >> 3);
    const int head = grp & 7;
    const int b = m >> 15;
    float2 r = refxy[m];
    const float* lg = aw + (size_t)m * 48 + head * 6;
    float l[6];
#pragma unroll
    for (int p = 0; p < 6; ++p) l[p] = lg[p];
    float mx = l[0];
#pragma unroll
    for (int p = 1; p < 6; ++p) mx = fmaxf(mx, l[p]);
    float s = 0.f;
#pragma unroll
    for (int p = 0; p < 6; ++p) { l[p] = expf(l[p] - mx); s += l[p]; }
    float inv = 1.f / s;
    const float* of = offs + (size_t)m * 96 + head * 12;
    const float* Vb = V + (size_t)b * 40000 * 128 + head * 16 + lane;
    float acc = 0.f;
#pragma unroll
    for (int p = 0; p < 6; ++p) {
        float px = r.x * 200.f + of[p * 2 + 0] - 0.5f;
        float py = r.y * 200.f + of[p * 2 + 1] - 0.5f;
        float fx = floorf(px), fy = floorf(py);
        int x0 = (int)fx, y0 = (int)fy;
        float wx = px - fx, wy = py - fy;
        float v00 = samp_v(Vb, x0, y0);
        float v10 = samp_v(Vb, x0 + 1, y0);
        float v01 = samp_v(Vb, x0, y0 + 1);
        float v11 = samp_v(Vb, x0 + 1, y0 + 1);
        float bil = v00 * (1.f - wx) * (1.f - wy) + v10 * wx * (1.f - wy) +
                    v01 * (1.f - wx) * wy + v11 * wx * wy;
        acc += l[p] * inv * bil;
    }
    out[(size_t)m * 128 + head * 16 + lane] = acc;
}

// ---------------- launch ----------------
extern "C" void kernel_launch(void* const* d_in, const int* in_sizes, int n_in,
                              void* d_out, int out_size, void* d_ws, size_t ws_size,
                              hipStream_t stream) {
    const float* x_rv = (const float*)d_in[0];
    const float* bev = (const float*)d_in[1];
    const float* pq_w = (const float*)d_in[2];
    const float* pq_b = (const float*)d_in[3];
    const float* pv_w = (const float*)d_in[4];
    const float* pv_b = (const float*)d_in[5];
    const float* po_w = (const float*)d_in[6];
    const float* po_b = (const float*)d_in[7];
    const float* qs_w1 = (const float*)d_in[8];
    const float* qs_b1 = (const float*)d_in[9];
    const float* qs_w2 = (const float*)d_in[10];
    const float* qs_b2 = (const float*)d_in[11];
    const float* rh_w1 = (const float*)d_in[12];
    const float* rh_b1 = (const float*)d_in[13];
    const float* rh_g1 = (const float*)d_in[14];
    const float* rh_be1 = (const float*)d_in[15];
    const float* rh_w2 = (const float*)d_in[16];
    const float* rh_g2 = (const float*)d_in[17];
    const float* rh_be2 = (const float*)d_in[18];
    const float* rh_w3 = (const float*)d_in[19];
    const float* rh_b3 = (const float*)d_in[20];
    const float* so_w = (const float*)d_in[21];
    const float* so_b = (const float*)d_in[22];
    const float* aw_w = (const float*)d_in[23];
    const float* aw_b = (const float*)d_in[24];
    const float* vp_w = (const float*)d_in[25];
    const float* vp_b = (const float*)d_in[26];
    const float* op_w = (const float*)d_in[27];
    const float* op_b = (const float*)d_in[28];

    const int M = 65536;

    float* ws = (float*)d_ws;
    float* azsc = ws;    ws += 2048;
    float* pvvp_w = ws;  ws += 256 * 128;
    float* pvvp_b = ws;  ws += 128;
    float* oppo_w = ws;  ws += 128 * 128;
    float* oppo_b = ws;  ws += 128;
    float* pqqs_w = ws;  ws += 64 * 128;
    float* pqqs_b = ws;  ws += 128;
    float* stats = ws;   ws += 64;
    float* Vv = ws;      ws += (size_t)80000 * 128;
    float* h1 = ws;      ws += (size_t)M * 128;
    float* h2 = ws;      ws += (size_t)M * 64;
    float* q1 = ws;      ws += (size_t)M * 128;
    float* refxy = ws;   ws += (size_t)M * 2;
    float* sigf = ws;    ws += (size_t)M * 2;
    size_t need_bytes = (size_t)(ws - (float*)d_ws) * sizeof(float);
    if (ws_size < need_bytes) return;
    float* query = h1;  // h1 free after conv
    float* offs = q1;   // q1 free after qs2
    float* attw = h2;   // h2 free after rh3 (M*64 >= M*48)
    float* mo = h1;     // query free after offs/attw

    float2* azsc2 = (float2*)azsc;
    float2* refxy2 = (float2*)refxy;
    float2* sigf2 = (float2*)sigf;

    azsc_kernel<<<4, 256, 0, stream>>>(azsc2);
    prep_weights<<<451, 128, 0, stream>>>(pv_w, pv_b, vp_w, vp_b, op_w, op_b, po_w, po_b,
                                          pq_w, pq_b, qs_w1, qs_b1,
                                          pvvp_w, pvvp_b, oppo_w, oppo_b, pqqs_w, pqqs_b);

    // value = bev^T @ (pv_w@vp_w) + fused bias
    value_gemm<<<dim3(625, 2), 256, 0, stream>>>(bev, pvvp_w, pvvp_b, Vv);

    // h1 = concat(x_rv, [sin,cos,0]) @ rh_w1 + rh_b1
    gemm_rn<64, 128, 256><<<M / 64, 256, 0, stream>>>(
        x_rv, 64, rh_w1, 128, rh_b1, h1, 128, 64, azsc2, nullptr, rh_w1 + 64 * 128, 1, 0);

    // GN1 + gelu (in place)
    hipMemsetAsync(stats, 0, 32 * sizeof(float), stream);
    gn_stats<128, 16, 128><<<512, 256, 0, stream>>>(h1, stats);
    gn_apply<128, 16><<<8192, 256, 0, stream>>>(h1, stats, rh_g1, rh_be1, 1.0f / 524288.0f);

    // 3x3 circular conv 128 -> 64 (un-normalized output)
    conv3x3_kernel<<<dim3(16, 32, 2), 256, 0, stream>>>(h1, rh_w2, h2);

    // GN2 stats, then fused GN2-apply+gelu+rh3
    hipMemsetAsync(stats, 0, 32 * sizeof(float), stream);
    gn_stats<64, 8, 128><<<512, 256, 0, stream>>>(h2, stats);
    rh3_kernel<<<4096, 256, 0, stream>>>(h2, stats, rh_g2, rh_be2, 1.0f / 262144.0f,
                                         rh_w3, rh_b3, azsc2, refxy2, sigf2);

    // q1 = gelu(x_rv @ (pq_w@qs_w1a) + sigf-extras + fused bias)   [Q0 eliminated]
    gemm_rn<64, 128, 256><<<M / 64, 256, 0, stream>>>(
        x_rv, 64, pqqs_w, 128, pqqs_b, q1, 128, 64, nullptr, sigf, qs_w1 + 128 * 128, 2, 1);

    // query = q1 @ qs_w2 + qs_b2  (into h1)
    gemm_rn<64, 128, 256><<<M / 64, 256, 0, stream>>>(
        q1, 128, qs_w2, 128, qs_b2, query, 128, 128, nullptr, nullptr, nullptr, 0, 0);

    // offs = query @ so_w + so_b  (into q1)
    gemm_rn<64, 96, 192><<<M / 64, 192, 0, stream>>>(
        query, 128, so_w, 96, so_b, offs, 96, 128, nullptr, nullptr, nullptr, 0, 0);

    // attw logits = query @ aw_w + aw_b  (into h2)
    gemm_rn<128, 48, 192><<<M / 128, 192, 0, stream>>>(
        query, 128, aw_w, 48, aw_b, attw, 48, 128, nullptr, nullptr, nullptr, 0, 0);

    // MSDA sampling (into h1; query dead)
    msda_kernel<<<M / 2, 256, 0, stream>>>(Vv, refxy2, offs, attw, mo);

    // y = mo @ (op_w@po_w) + fused bias  -> d_out
    gemm_rn<64, 128, 256><<<M / 64, 256, 0, stream>>>(
        mo, 128, oppo_w, 128, oppo_b, (float*)d_out, 128, 128, nullptr, nullptr, nullptr, 0, 0);
}